// Round 20
// baseline (83.361 us; speedup 1.0000x reference)
//
#include <hip/hip_runtime.h>
#include <math.h>

#define BB   8
#define HH   8
#define DDIM 64
#define NN   1024
#define HID  512
#define COUT 320

typedef float4 f4;
typedef __bf16 bf16;
typedef __attribute__((ext_vector_type(8))) __bf16 bf16x8;
typedef __attribute__((ext_vector_type(4))) __bf16 bf16x4;
typedef __attribute__((ext_vector_type(4))) float f32x4;

#define MFMA16(a,b,c) __builtin_amdgcn_mfma_f32_16x16x32_bf16((a),(b),(c),0,0,0)

__device__ __forceinline__ void gll16(const bf16* g, char* l) {
    __builtin_amdgcn_global_load_lds(
        (const __attribute__((address_space(1))) void*)g,
        (__attribute__((address_space(3))) void*)l, 16, 0, 0);
}

// ---------------------------------------------------------------------------
// Prep bodies (verified rounds 3-18; Xs stride 69)
// ---------------------------------------------------------------------------
template<int CIN>
__device__ __forceinline__
void conv_w_body(const float* __restrict__ W, bf16* __restrict__ Wh,
                 bf16* __restrict__ Wl, int rows_valid, int bx)
{
    const int idx = bx * 256 + threadIdx.x;
    const int row = idx / (CIN / 4);
    const int c4  = (idx % (CIN / 4)) * 4;
    f4 v = {0.f, 0.f, 0.f, 0.f};
    if (row < rows_valid) v = *(const f4*)&W[(size_t)row * CIN + c4];
    const float vv[4] = {v.x, v.y, v.z, v.w};
    bf16x4 hv, lv;
#pragma unroll
    for (int e = 0; e < 4; ++e) {
        bf16 hb = (bf16)vv[e];
        hv[e] = hb;
        lv[e] = (bf16)(vv[e] - (float)hb);
    }
    *(bf16x4*)&Wh[(size_t)row * CIN + c4] = hv;
    if (Wl) *(bf16x4*)&Wl[(size_t)row * CIN + c4] = lv;
}

template<int CIN>
__device__ __forceinline__
void conv_xt_body(const float* __restrict__ X, bf16* __restrict__ Xt,
                  float (*Xs)[69], int bx, int by, int bz)
{
    const int n0 = bx * 64;
    const int c0 = by * 64;
    const int t  = threadIdx.x;
    const float* Xb = X + (size_t)bz * CIN * NN;
#pragma unroll
    for (int it = 0; it < 4; ++it) {
        const int r  = it * 16 + (t >> 4);
        const int cc = (t & 15) * 4;
        *(f4*)&Xs[r][cc] = *(const f4*)&Xb[(size_t)(c0 + r) * NN + n0 + cc];
    }
    __syncthreads();
    const int n  = t >> 2;
    const int cb = (t & 3) * 16;
    union { bf16 h[16]; uint4 u[2]; } o;
#pragma unroll
    for (int e = 0; e < 16; ++e) o.h[e] = (bf16)Xs[cb + e][n];
    bf16* dst = Xt + ((size_t)bz * NN + n0 + n) * CIN + c0 + cb;
    *(uint4*)dst = o.u[0];
    *(uint4*)(dst + 8) = o.u[1];
}

__global__ __launch_bounds__(256)
void prep_kernel(const float* __restrict__ x_q, const float* __restrict__ x_kv,
                 const float* __restrict__ w_q, const float* __restrict__ w_kv,
                 const float* __restrict__ w_out,
                 bf16* __restrict__ Xtq, bf16* __restrict__ Xtkv,
                 bf16* __restrict__ Wqh,
                 bf16* __restrict__ Wkvh,
                 bf16* __restrict__ Wouth, bf16* __restrict__ Woutl)
{
    __shared__ __align__(16) float Xs[64][69];
    const int id = blockIdx.x;
    if (id < 640) {
        const int r = id >> 4;
        conv_xt_body<320>(x_q, Xtq, Xs, id & 15, r % 5, r / 5);
    } else if (id < 1920) {
        const int i = id - 640, r = i >> 4;
        conv_xt_body<640>(x_kv, Xtkv, Xs, i & 15, r % 10, r / 10);
    } else if (id < 2080) {
        conv_w_body<320>(w_q, Wqh, nullptr, 512, id - 1920);
    } else if (id < 2720) {
        conv_w_body<640>(w_kv, Wkvh, nullptr, 1024, id - 2080);
    } else {
        conv_w_body<512>(w_out, Wouth, Woutl, 320, id - 2720);
    }
}

// ---------------------------------------------------------------------------
// Split-bf16 MFMA GEMM body (verified r7-r18): global_load_lds staging,
// double-buffered LDS, counted-vmcnt 2-phase pipeline.
// TERMS=1 compact buffers {A@0,B@8K} (16KB); TERMS=2 {A@0,X@8K,B@16K} (24KB).
// ---------------------------------------------------------------------------
template<int K, int TERMS, int ASPLIT, int EPI>
__device__ __forceinline__
void gemm_body(char* lds,
               const bf16* __restrict__ Ah, const bf16* __restrict__ Al,
               const bf16* __restrict__ Bh, const bf16* __restrict__ Bl,
               long a_bstride, long b_bstride,
               bf16* __restrict__ D0,
               float* __restrict__ Df, float scale,
               int bx, int by, int bz)
{
    constexpr int BUFB = (TERMS == 2) ? 24576 : 16384;
    constexpr int BOFF = (TERMS == 2) ? 16384 : 8192;

    const int t  = threadIdx.x;
    const int w  = t >> 6, l = t & 63;
    const int lg = l >> 4, lq = l & 15;
    const int wa = w >> 1, wb = w & 1;
    const int arow0 = by * 128;
    const int brow0 = bx * 128;

    const bf16* Ab = Ah + (size_t)bz * a_bstride;
    const bf16* Bb = Bh + (size_t)bz * b_bstride;

    const int srow = 16 * w + (l >> 2);
    const int cw   = (l & 3) ^ ((l >> 3) & 3);
    const bf16* pA = Ab + (size_t)(arow0 + srow) * K + cw * 8;
    const bf16* pB = Bb + (size_t)(brow0 + srow) * K + cw * 8;
    const bf16* pX = nullptr;
    if constexpr (TERMS == 2) {
        const bf16* Xb = ASPLIT ? (Al + (size_t)bz * a_bstride)
                                : (Bl + (size_t)bz * b_bstride);
        pX = Xb + (size_t)((ASPLIT ? arow0 : brow0) + srow) * K + cw * 8;
    }
    const int woff = w * 1024;

    f32x4 acc[4][4];
#pragma unroll
    for (int i = 0; i < 4; ++i)
#pragma unroll
        for (int j = 0; j < 4; ++j) acc[i][j] = (f32x4){0.f, 0.f, 0.f, 0.f};

    constexpr int NK = K / 32;

    auto issue = [&](int ks2, int pbuf) {
        char* Bd = lds + pbuf * BUFB + woff;
        const int ko = ks2 * 32;
        gll16(pA + ko,          Bd);
        gll16(pA + 64 * K + ko, Bd + 4096);
        if constexpr (TERMS == 2) {
            gll16(pX + ko,          Bd + 8192);
            gll16(pX + 64 * K + ko, Bd + 8192 + 4096);
        }
        gll16(pB + ko,          Bd + BOFF);
        gll16(pB + 64 * K + ko, Bd + BOFF + 4096);
    };

    issue(0, 0);

    for (int ks = 0; ks < NK; ++ks) {
        const int p = ks & 1;
        if (ks + 1 < NK) {
            issue(ks + 1, p ^ 1);
            if constexpr (TERMS == 2)
                asm volatile("s_waitcnt vmcnt(6)" ::: "memory");
            else
                asm volatile("s_waitcnt vmcnt(4)" ::: "memory");
        } else {
            asm volatile("s_waitcnt vmcnt(0)" ::: "memory");
        }
        __builtin_amdgcn_s_barrier();
        __builtin_amdgcn_sched_barrier(0);

        char* buf = lds + p * BUFB;
        bf16x8 a0[4], a1[4], b0[4], b1[4];
#pragma unroll
        for (int m = 0; m < 4; ++m) {
            const int rA = wa * 64 + 16 * m + lq;
            const int offA = rA * 64 + ((lg ^ ((rA >> 1) & 3)) << 4);
            a0[m] = *(const bf16x8*)(buf + offA);
            if (TERMS == 2 && ASPLIT) a1[m] = *(const bf16x8*)(buf + 8192 + offA);
            const int rB = wb * 64 + 16 * m + lq;
            const int offB = rB * 64 + ((lg ^ ((rB >> 1) & 3)) << 4);
            b0[m] = *(const bf16x8*)(buf + BOFF + offB);
            if (TERMS == 2 && !ASPLIT) b1[m] = *(const bf16x8*)(buf + 8192 + offB);
        }
        __builtin_amdgcn_s_setprio(1);
#pragma unroll
        for (int mA = 0; mA < 4; ++mA)
#pragma unroll
            for (int mB = 0; mB < 4; ++mB) {
                acc[mA][mB] = MFMA16(a0[mA], b0[mB], acc[mA][mB]);
                if constexpr (TERMS == 2) {
                    acc[mA][mB] = ASPLIT ? MFMA16(a1[mA], b0[mB], acc[mA][mB])
                                         : MFMA16(a0[mA], b1[mB], acc[mA][mB]);
                }
            }
        __builtin_amdgcn_s_setprio(0);
        asm volatile("s_waitcnt lgkmcnt(0)" ::: "memory");
        __builtin_amdgcn_s_barrier();
        __builtin_amdgcn_sched_barrier(0);
    }

#pragma unroll
    for (int mA = 0; mA < 4; ++mA)
#pragma unroll
        for (int mB = 0; mB < 4; ++mB) {
            if (EPI == 4) {
                const int o = arow0 + wa * 64 + 16 * mA + 4 * lg;
                const int i = brow0 + wb * 64 + 16 * mB + lq;
                const int h = o >> 6, d = o & 63;
                const size_t base = ((size_t)((bz * HH + h) * NN + i)) * 64 + d;
                bf16x4 hv;
#pragma unroll
                for (int r = 0; r < 4; ++r) hv[r] = (bf16)(acc[mA][mB][r] * scale);
                *(bf16x4*)(D0 + base) = hv;
            } else if (EPI == 2) {
                const int i = arow0 + wa * 64 + 16 * mA + 4 * lg;
                const int o = brow0 + wb * 64 + 16 * mB + lq;
                const int h = o >> 6, d = o & 63;
                const size_t base = ((size_t)((bz * HH + h) * DDIM + d)) * NN + i;
                bf16x4 pv;
#pragma unroll
                for (int r = 0; r < 4; ++r) pv[r] = (bf16)acc[mA][mB][r];
                *(bf16x4*)(D0 + base) = pv;
            } else {
                const int i = arow0 + wa * 64 + 16 * mA + 4 * lg;
                const int o = brow0 + wb * 64 + 16 * mB + lq;
                if (o < COUT)
                    *(f32x4*)(Df + ((size_t)(bz * COUT + o)) * NN + i) = acc[mA][mB];
            }
        }
}

// log2(e) folded into Q scale: softmax runs in exp2 domain.
#define QSCALE (0.125f * 1.44269504f)

// All sub-GEMMs are TERMS=1 -> 32KB LDS, 4 blocks/CU.
__global__ __launch_bounds__(256, 4)
void gemm_qkv_kernel(const bf16* __restrict__ Xtq, const bf16* __restrict__ Xtkv,
                     const bf16* __restrict__ Wqh, const bf16* __restrict__ Wkvh,
                     bf16* __restrict__ Qhi, bf16* __restrict__ Khi,
                     bf16* __restrict__ Vt)
{
    __shared__ __align__(16) char lds[32768];
    const int id = blockIdx.x;
    if (id < 256) {
        gemm_body<320, 1, 0, 4>(lds, Wqh, nullptr, Xtq, nullptr, 0, (long)NN * 320,
                                Qhi, nullptr, QSCALE,
                                id & 7, (id >> 3) & 3, id >> 5);
    } else if (id < 512) {
        const int i = id - 256;
        gemm_body<640, 1, 0, 4>(lds, Wkvh, nullptr, Xtkv, nullptr, 0, (long)NN * 640,
                                Khi, nullptr, 1.0f,
                                i & 7, (i >> 3) & 3, i >> 5);
    } else {
        const int i = id - 512;
        gemm_body<640, 1, 0, 2>(lds, Xtkv, nullptr,
                                Wkvh + (size_t)HID * 640, nullptr,
                                (long)NN * 640, 0, Vt, nullptr, 1.0f,
                                i & 3, (i >> 2) & 7, i >> 5);
    }
}

__global__ __launch_bounds__(256, 2)
void outproj_kernel(const bf16* __restrict__ Ot,
                    const bf16* __restrict__ Wouth, const bf16* __restrict__ Woutl,
                    float* __restrict__ out)
{
    __shared__ __align__(16) char lds[49152];
    gemm_body<512, 2, 0, 3>(lds, Ot, nullptr, Wouth, Woutl, (long)NN * HID, 0,
                            nullptr, out, 1.0f,
                            blockIdx.x, blockIdx.y, blockIdx.z);
}

// ---------------------------------------------------------------------------
// MFMA flash attention, round 20: 1024 threads = 16 waves, 256 q-rows/block,
// grid 256 (1 block/CU x 16 waves = 16 waves/CU, unchanged). Per-wave inner
// code identical to r19. Staging: waves 0-7 stage the K tile (8 rows each),
// waves 8-15 stage V — exactly 1 gll16/thread/tile, vmcnt(1); K/V fetched
// once per 256 q.
// LDS 65536: [0,16K) buf0 {K 8K,V 8K}; [16K,32K) buf1; [32K,64K) P (2K/wave).
// ---------------------------------------------------------------------------
__global__ __launch_bounds__(1024, 1)
void attn_kernel(const bf16* __restrict__ Qhi, const bf16* __restrict__ Khi,
                 const bf16* __restrict__ Vt, bf16* __restrict__ Ot)
{
    const int id  = blockIdx.x;
    const int loc = id >> 3;                     // 0..31
    const int bh  = (id & 7) * 8 + (loc >> 2);   // 8 bh per XCD
    const int i0  = (loc & 3) * 256;
    const int b   = bh >> 3, h = bh & 7;
    const int t   = threadIdx.x;
    const int w   = t >> 6;       // 0..15
    const int l   = t & 63;
    const int lg  = l >> 4;
    const int lq  = l & 15;

    __shared__ __align__(16) char lds[65536];

    // Q fragments: wave w owns q rows [i0+16w, i0+16w+16)
    const size_t qbase = ((size_t)(bh * NN) + i0 + w * 16 + lq) * DDIM + lg * 8;
    bf16x8 qh[2];
    qh[0] = *(const bf16x8*)(Qhi + qbase);
    qh[1] = *(const bf16x8*)(Qhi + qbase + 32);

    // staging: waves 0-7 stage K rows [8w,8w+8); waves 8-15 stage V rows
    // [8(w-8), +8). lane l covers row base + (l>>3), slot-chunk l&7, source
    // chunk (l&7)^(row&7). Per-tile source step: K = 64 rows * 64 = 4096
    // elems; V = 64 columns.
    const int w8   = w & 7;
    const bool isV = w >= 8;
    const int srow = 8 * w8 + (l >> 3);
    const int cw   = (l & 7) ^ (srow & 7);
    const bf16* src = isV
        ? Vt  + (((size_t)(bh * DDIM) + srow) << 10) + cw * 8
        : Khi + ((size_t)(bh * NN) + srow) * DDIM + cw * 8;
    const int step = isV ? 64 : 4096;
    char* const Lw = lds + (isV ? 8192 : 0) + (w8 << 10);

    f32x4 Oa[4];
#pragma unroll
    for (int m = 0; m < 4; ++m) { Oa[m][0]=0.f; Oa[m][1]=0.f; Oa[m][2]=0.f; Oa[m][3]=0.f; }
    float l_lane = 0.f;

    char* Pw = lds + 32768 + w * 2048;

    gll16(src, Lw);

    for (int jt = 0; jt < 16; ++jt) {
        const int p = jt & 1;
        if (jt < 15) {
            gll16(src + (size_t)(jt + 1) * step, Lw + 16384 * (p ^ 1));
            asm volatile("s_waitcnt vmcnt(1)" ::: "memory");
        } else {
            asm volatile("s_waitcnt vmcnt(0)" ::: "memory");
        }
        __builtin_amdgcn_s_barrier();
        __builtin_amdgcn_sched_barrier(0);

        char* buf = lds + 16384 * p;

        // ---- St = K·Q^T (rows j, cols q); 1-term ----
        f32x4 S[4];
        __builtin_amdgcn_s_setprio(1);
#pragma unroll
        for (int m = 0; m < 4; ++m) {
            f32x4 acc = {0.f, 0.f, 0.f, 0.f};
#pragma unroll
            for (int ks = 0; ks < 2; ++ks) {
                const int row = lq + 16 * m;
                const int ch  = ((lg + 4 * ks) ^ (row & 7)) << 4;
                bf16x8 kh = *(const bf16x8*)(buf + row * 128 + ch);
                acc = MFMA16(kh, qh[ks], acc);
            }
            S[m] = acc;
        }
        __builtin_amdgcn_s_setprio(0);

        // ---- softmax numerator (exp2, fixed max) ----
        float ps[4][4];
#pragma unroll
        for (int m = 0; m < 4; ++m)
#pragma unroll
            for (int r = 0; r < 4; ++r) {
                const float p2 = __builtin_exp2f(S[m][r]);
                ps[m][r] = p2;
                l_lane += p2;
            }

        // ---- P -> per-wave LDS region (bf16) ----
#pragma unroll
        for (int f = 0; f < 4; ++f) {
            union { bf16 hh[4]; uint2 u; } pu;
            pu.hh[0] = (bf16)ps[f][0];
            pu.hh[1] = (bf16)ps[f][1];
            pu.hh[2] = (bf16)ps[f][2];
            pu.hh[3] = (bf16)ps[f][3];
            *(uint2*)(Pw + lq * 128 + (((2 * f + (lg >> 1)) ^ (lq & 7)) << 4) + ((lg & 1) << 3)) = pu.u;
        }

        // ---- Ot += Vt · Pt ----
#pragma unroll
        for (int ks = 0; ks < 2; ++ks) {
            bf16x8 pb = *(const bf16x8*)(Pw + lq * 128 + (((lg + 4 * ks) ^ (lq & 7)) << 4));
            __builtin_amdgcn_s_setprio(1);
#pragma unroll
            for (int m = 0; m < 4; ++m) {
                const int row = lq + 16 * m;
                bf16x8 va = *(const bf16x8*)(buf + 8192 + row * 128 + (((lg + 4 * ks) ^ (row & 7)) << 4));
                Oa[m] = MFMA16(va, pb, Oa[m]);
            }
            __builtin_amdgcn_s_setprio(0);
        }

        asm volatile("s_waitcnt lgkmcnt(0)" ::: "memory");
        __builtin_amdgcn_s_barrier();
        __builtin_amdgcn_sched_barrier(0);
    }

    // epilogue: cross-lane l-reduction (lanes lq, lq+16, lq+32, lq+48)
    float l_run = l_lane;
    l_run += __shfl_xor(l_run, 16);
    l_run += __shfl_xor(l_run, 32);
    const float inv = 1.0f / l_run;
    const int i = i0 + w * 16 + lq;
    const size_t obase = ((size_t)(b * NN) + i) * HID + h * DDIM;
#pragma unroll
    for (int m = 0; m < 4; ++m) {
        bf16x4 ov;
#pragma unroll
        for (int r = 0; r < 4; ++r) ov[r] = (bf16)(Oa[m][r] * inv);
        *(bf16x4*)(Ot + obase + 16 * m + 4 * lg) = ov;
    }
}

// ---------------------------------------------------------------------------
extern "C" void kernel_launch(void* const* d_in, const int* in_sizes, int n_in,
                              void* d_out, int out_size, void* d_ws, size_t ws_size,
                              hipStream_t stream)
{
    const float* x_q   = (const float*)d_in[0];
    const float* x_kv  = (const float*)d_in[1];
    const float* w_q   = (const float*)d_in[2];
    const float* w_kv  = (const float*)d_in[3];
    const float* w_out = (const float*)d_in[4];
    float* out = (float*)d_out;

    char* ws = (char*)d_ws;
    bf16* Xtq   = (bf16*)(ws + 0);
    bf16* Ot    = (bf16*)(ws + 0);
    bf16* Xtkv  = (bf16*)(ws + 5242880);
    bf16* Wqh   = (bf16*)(ws + 15728640);
    bf16* Wkvh  = (bf16*)(ws + 16384000);
    bf16* Wouth = (bf16*)(ws + 19005440);
    bf16* Woutl = (bf16*)(ws + 19398656);
    bf16* Qhi   = (bf16*)(ws + 19791872);
    bf16* Khi   = (bf16*)(ws + 36569088);
    bf16* Vt    = (bf16*)(ws + 53346304);

    dim3 blk(256);
    prep_kernel<<<dim3(2912), blk, 0, stream>>>(x_q, x_kv, w_q, w_kv, w_out,
                                                Xtq, Xtkv, Wqh, Wkvh,
                                                Wouth, Woutl);
    gemm_qkv_kernel<<<dim3(768), blk, 0, stream>>>(Xtq, Xtkv, Wqh, Wkvh,
                                                   Qhi, Khi, Vt);
    attn_kernel<<<dim3(256), dim3(1024), 0, stream>>>(Qhi, Khi, Vt, Ot);
    outproj_kernel<<<dim3(3, 8, 8), blk, 0, stream>>>(Ot, Wouth, Woutl, out);
}

// Round 21
// 82.491 us; speedup vs baseline: 1.0105x; 1.0105x over previous
//
#include <hip/hip_runtime.h>
#include <math.h>

#define BB   8
#define HH   8
#define DDIM 64
#define NN   1024
#define HID  512
#define COUT 320

typedef float4 f4;
typedef __bf16 bf16;
typedef __attribute__((ext_vector_type(8))) __bf16 bf16x8;
typedef __attribute__((ext_vector_type(4))) __bf16 bf16x4;
typedef __attribute__((ext_vector_type(4))) float f32x4;

#define MFMA16(a,b,c) __builtin_amdgcn_mfma_f32_16x16x32_bf16((a),(b),(c),0,0,0)

__device__ __forceinline__ void gll16(const bf16* g, char* l) {
    __builtin_amdgcn_global_load_lds(
        (const __attribute__((address_space(1))) void*)g,
        (__attribute__((address_space(3))) void*)l, 16, 0, 0);
}

// ---------------------------------------------------------------------------
// Prep bodies (verified rounds 3-18; Xs stride 69)
// ---------------------------------------------------------------------------
template<int CIN>
__device__ __forceinline__
void conv_w_body(const float* __restrict__ W, bf16* __restrict__ Wh,
                 bf16* __restrict__ Wl, int rows_valid, int bx)
{
    const int idx = bx * 256 + threadIdx.x;
    const int row = idx / (CIN / 4);
    const int c4  = (idx % (CIN / 4)) * 4;
    f4 v = {0.f, 0.f, 0.f, 0.f};
    if (row < rows_valid) v = *(const f4*)&W[(size_t)row * CIN + c4];
    const float vv[4] = {v.x, v.y, v.z, v.w};
    bf16x4 hv, lv;
#pragma unroll
    for (int e = 0; e < 4; ++e) {
        bf16 hb = (bf16)vv[e];
        hv[e] = hb;
        lv[e] = (bf16)(vv[e] - (float)hb);
    }
    *(bf16x4*)&Wh[(size_t)row * CIN + c4] = hv;
    if (Wl) *(bf16x4*)&Wl[(size_t)row * CIN + c4] = lv;
}

template<int CIN>
__device__ __forceinline__
void conv_xt_body(const float* __restrict__ X, bf16* __restrict__ Xt,
                  float (*Xs)[69], int bx, int by, int bz)
{
    const int n0 = bx * 64;
    const int c0 = by * 64;
    const int t  = threadIdx.x;
    const float* Xb = X + (size_t)bz * CIN * NN;
#pragma unroll
    for (int it = 0; it < 4; ++it) {
        const int r  = it * 16 + (t >> 4);
        const int cc = (t & 15) * 4;
        *(f4*)&Xs[r][cc] = *(const f4*)&Xb[(size_t)(c0 + r) * NN + n0 + cc];
    }
    __syncthreads();
    const int n  = t >> 2;
    const int cb = (t & 3) * 16;
    union { bf16 h[16]; uint4 u[2]; } o;
#pragma unroll
    for (int e = 0; e < 16; ++e) o.h[e] = (bf16)Xs[cb + e][n];
    bf16* dst = Xt + ((size_t)bz * NN + n0 + n) * CIN + c0 + cb;
    *(uint4*)dst = o.u[0];
    *(uint4*)(dst + 8) = o.u[1];
}

__global__ __launch_bounds__(256)
void prep_kernel(const float* __restrict__ x_q, const float* __restrict__ x_kv,
                 const float* __restrict__ w_q, const float* __restrict__ w_kv,
                 const float* __restrict__ w_out,
                 bf16* __restrict__ Xtq, bf16* __restrict__ Xtkv,
                 bf16* __restrict__ Wqh,
                 bf16* __restrict__ Wkvh,
                 bf16* __restrict__ Wouth, bf16* __restrict__ Woutl)
{
    __shared__ __align__(16) float Xs[64][69];
    const int id = blockIdx.x;
    if (id < 640) {
        const int r = id >> 4;
        conv_xt_body<320>(x_q, Xtq, Xs, id & 15, r % 5, r / 5);
    } else if (id < 1920) {
        const int i = id - 640, r = i >> 4;
        conv_xt_body<640>(x_kv, Xtkv, Xs, i & 15, r % 10, r / 10);
    } else if (id < 2080) {
        conv_w_body<320>(w_q, Wqh, nullptr, 512, id - 1920);
    } else if (id < 2720) {
        conv_w_body<640>(w_kv, Wkvh, nullptr, 1024, id - 2080);
    } else {
        conv_w_body<512>(w_out, Wouth, Woutl, 320, id - 2720);
    }
}

// ---------------------------------------------------------------------------
// Split-bf16 MFMA GEMM body (verified r7-r18): global_load_lds staging,
// double-buffered LDS, counted-vmcnt 2-phase pipeline.
// TERMS=1 compact buffers {A@0,B@8K} (16KB); TERMS=2 {A@0,X@8K,B@16K} (24KB).
// ---------------------------------------------------------------------------
template<int K, int TERMS, int ASPLIT, int EPI>
__device__ __forceinline__
void gemm_body(char* lds,
               const bf16* __restrict__ Ah, const bf16* __restrict__ Al,
               const bf16* __restrict__ Bh, const bf16* __restrict__ Bl,
               long a_bstride, long b_bstride,
               bf16* __restrict__ D0,
               float* __restrict__ Df, float scale,
               int bx, int by, int bz)
{
    constexpr int BUFB = (TERMS == 2) ? 24576 : 16384;
    constexpr int BOFF = (TERMS == 2) ? 16384 : 8192;

    const int t  = threadIdx.x;
    const int w  = t >> 6, l = t & 63;
    const int lg = l >> 4, lq = l & 15;
    const int wa = w >> 1, wb = w & 1;
    const int arow0 = by * 128;
    const int brow0 = bx * 128;

    const bf16* Ab = Ah + (size_t)bz * a_bstride;
    const bf16* Bb = Bh + (size_t)bz * b_bstride;

    const int srow = 16 * w + (l >> 2);
    const int cw   = (l & 3) ^ ((l >> 3) & 3);
    const bf16* pA = Ab + (size_t)(arow0 + srow) * K + cw * 8;
    const bf16* pB = Bb + (size_t)(brow0 + srow) * K + cw * 8;
    const bf16* pX = nullptr;
    if constexpr (TERMS == 2) {
        const bf16* Xb = ASPLIT ? (Al + (size_t)bz * a_bstride)
                                : (Bl + (size_t)bz * b_bstride);
        pX = Xb + (size_t)((ASPLIT ? arow0 : brow0) + srow) * K + cw * 8;
    }
    const int woff = w * 1024;

    f32x4 acc[4][4];
#pragma unroll
    for (int i = 0; i < 4; ++i)
#pragma unroll
        for (int j = 0; j < 4; ++j) acc[i][j] = (f32x4){0.f, 0.f, 0.f, 0.f};

    constexpr int NK = K / 32;

    auto issue = [&](int ks2, int pbuf) {
        char* Bd = lds + pbuf * BUFB + woff;
        const int ko = ks2 * 32;
        gll16(pA + ko,          Bd);
        gll16(pA + 64 * K + ko, Bd + 4096);
        if constexpr (TERMS == 2) {
            gll16(pX + ko,          Bd + 8192);
            gll16(pX + 64 * K + ko, Bd + 8192 + 4096);
        }
        gll16(pB + ko,          Bd + BOFF);
        gll16(pB + 64 * K + ko, Bd + BOFF + 4096);
    };

    issue(0, 0);

    for (int ks = 0; ks < NK; ++ks) {
        const int p = ks & 1;
        if (ks + 1 < NK) {
            issue(ks + 1, p ^ 1);
            if constexpr (TERMS == 2)
                asm volatile("s_waitcnt vmcnt(6)" ::: "memory");
            else
                asm volatile("s_waitcnt vmcnt(4)" ::: "memory");
        } else {
            asm volatile("s_waitcnt vmcnt(0)" ::: "memory");
        }
        __builtin_amdgcn_s_barrier();
        __builtin_amdgcn_sched_barrier(0);

        char* buf = lds + p * BUFB;
        bf16x8 a0[4], a1[4], b0[4], b1[4];
#pragma unroll
        for (int m = 0; m < 4; ++m) {
            const int rA = wa * 64 + 16 * m + lq;
            const int offA = rA * 64 + ((lg ^ ((rA >> 1) & 3)) << 4);
            a0[m] = *(const bf16x8*)(buf + offA);
            if (TERMS == 2 && ASPLIT) a1[m] = *(const bf16x8*)(buf + 8192 + offA);
            const int rB = wb * 64 + 16 * m + lq;
            const int offB = rB * 64 + ((lg ^ ((rB >> 1) & 3)) << 4);
            b0[m] = *(const bf16x8*)(buf + BOFF + offB);
            if (TERMS == 2 && !ASPLIT) b1[m] = *(const bf16x8*)(buf + 8192 + offB);
        }
        __builtin_amdgcn_s_setprio(1);
#pragma unroll
        for (int mA = 0; mA < 4; ++mA)
#pragma unroll
            for (int mB = 0; mB < 4; ++mB) {
                acc[mA][mB] = MFMA16(a0[mA], b0[mB], acc[mA][mB]);
                if constexpr (TERMS == 2) {
                    acc[mA][mB] = ASPLIT ? MFMA16(a1[mA], b0[mB], acc[mA][mB])
                                         : MFMA16(a0[mA], b1[mB], acc[mA][mB]);
                }
            }
        __builtin_amdgcn_s_setprio(0);
        asm volatile("s_waitcnt lgkmcnt(0)" ::: "memory");
        __builtin_amdgcn_s_barrier();
        __builtin_amdgcn_sched_barrier(0);
    }

#pragma unroll
    for (int mA = 0; mA < 4; ++mA)
#pragma unroll
        for (int mB = 0; mB < 4; ++mB) {
            if (EPI == 4) {
                const int o = arow0 + wa * 64 + 16 * mA + 4 * lg;
                const int i = brow0 + wb * 64 + 16 * mB + lq;
                const int h = o >> 6, d = o & 63;
                const size_t base = ((size_t)((bz * HH + h) * NN + i)) * 64 + d;
                bf16x4 hv;
#pragma unroll
                for (int r = 0; r < 4; ++r) hv[r] = (bf16)(acc[mA][mB][r] * scale);
                *(bf16x4*)(D0 + base) = hv;
            } else if (EPI == 2) {
                const int i = arow0 + wa * 64 + 16 * mA + 4 * lg;
                const int o = brow0 + wb * 64 + 16 * mB + lq;
                const int h = o >> 6, d = o & 63;
                const size_t base = ((size_t)((bz * HH + h) * DDIM + d)) * NN + i;
                bf16x4 pv;
#pragma unroll
                for (int r = 0; r < 4; ++r) pv[r] = (bf16)acc[mA][mB][r];
                *(bf16x4*)(D0 + base) = pv;
            } else {
                const int i = arow0 + wa * 64 + 16 * mA + 4 * lg;
                const int o = brow0 + wb * 64 + 16 * mB + lq;
                if (o < COUT)
                    *(f32x4*)(Df + ((size_t)(bz * COUT + o)) * NN + i) = acc[mA][mB];
            }
        }
}

// log2(e) folded into Q scale: softmax runs in exp2 domain.
#define QSCALE (0.125f * 1.44269504f)

// All sub-GEMMs are TERMS=1 -> 32KB LDS, 4 blocks/CU.
__global__ __launch_bounds__(256, 4)
void gemm_qkv_kernel(const bf16* __restrict__ Xtq, const bf16* __restrict__ Xtkv,
                     const bf16* __restrict__ Wqh, const bf16* __restrict__ Wkvh,
                     bf16* __restrict__ Qhi, bf16* __restrict__ Khi,
                     bf16* __restrict__ Vt)
{
    __shared__ __align__(16) char lds[32768];
    const int id = blockIdx.x;
    if (id < 256) {
        gemm_body<320, 1, 0, 4>(lds, Wqh, nullptr, Xtq, nullptr, 0, (long)NN * 320,
                                Qhi, nullptr, QSCALE,
                                id & 7, (id >> 3) & 3, id >> 5);
    } else if (id < 512) {
        const int i = id - 256;
        gemm_body<640, 1, 0, 4>(lds, Wkvh, nullptr, Xtkv, nullptr, 0, (long)NN * 640,
                                Khi, nullptr, 1.0f,
                                i & 7, (i >> 3) & 3, i >> 5);
    } else {
        const int i = id - 512;
        gemm_body<640, 1, 0, 2>(lds, Xtkv, nullptr,
                                Wkvh + (size_t)HID * 640, nullptr,
                                (long)NN * 640, 0, Vt, nullptr, 1.0f,
                                i & 3, (i >> 2) & 7, i >> 5);
    }
}

__global__ __launch_bounds__(256, 2)
void outproj_kernel(const bf16* __restrict__ Ot,
                    const bf16* __restrict__ Wouth, const bf16* __restrict__ Woutl,
                    float* __restrict__ out)
{
    __shared__ __align__(16) char lds[49152];
    gemm_body<512, 2, 0, 3>(lds, Ot, nullptr, Wouth, Woutl, (long)NN * HID, 0,
                            nullptr, out, 1.0f,
                            blockIdx.x, blockIdx.y, blockIdx.z);
}

// ---------------------------------------------------------------------------
// MFMA flash attention (r19 verified best): 512 threads = 8 waves, 128
// q-rows/block, grid 512 (2 blocks/CU x 8 waves = 16 waves/CU). Per-wave
// inner code = verified r12 structure (16 q rows, fixed-max exp2 softmax,
// dedicated P region, 2 barriers/tile). K/V staging split across 8 waves:
// 2 gll16/thread/tile, vmcnt(2).
// LDS 49152: [0,16K) buf0 {K 8K,V 8K}; [16K,32K) buf1; [32K,48K) P (2K/wave).
// ---------------------------------------------------------------------------
__global__ __launch_bounds__(512, 2)
void attn_kernel(const bf16* __restrict__ Qhi, const bf16* __restrict__ Khi,
                 const bf16* __restrict__ Vt, bf16* __restrict__ Ot)
{
    const int id  = blockIdx.x;
    const int loc = id >> 3;
    const int bh  = (id & 7) * 8 + (loc >> 3);   // 8 bh per XCD
    const int i0  = (loc & 7) * 128;
    const int b   = bh >> 3, h = bh & 7;
    const int t   = threadIdx.x;
    const int w   = t >> 6;       // 0..7
    const int l   = t & 63;
    const int lg  = l >> 4;
    const int lq  = l & 15;

    __shared__ __align__(16) char lds[49152];

    const size_t qbase = ((size_t)(bh * NN) + i0 + w * 16 + lq) * DDIM + lg * 8;
    bf16x8 qh[2];
    qh[0] = *(const bf16x8*)(Qhi + qbase);
    qh[1] = *(const bf16x8*)(Qhi + qbase + 32);

    const int srow = 8 * w + (l >> 3);
    const int cw = (l & 7) ^ (srow & 7);
    const bf16* KhS = Khi + ((size_t)(bh * NN) + srow) * DDIM + cw * 8;
    const bf16* VS  = Vt  + (((size_t)(bh * DDIM) + srow) << 10) + cw * 8;
    char* const Lw = lds + (w << 10);

    f32x4 Oa[4];
#pragma unroll
    for (int m = 0; m < 4; ++m) { Oa[m][0]=0.f; Oa[m][1]=0.f; Oa[m][2]=0.f; Oa[m][3]=0.f; }
    float l_lane = 0.f;

    char* Pw = lds + 32768 + w * 2048;

    {
        gll16(KhS, Lw);
        gll16(VS,  Lw + 8192);
    }

    for (int jt = 0; jt < 16; ++jt) {
        const int p = jt & 1;
        if (jt < 15) {
            char* B = Lw + 16384 * (p ^ 1);
            gll16(KhS + ((size_t)(jt + 1) << 12), B);
            gll16(VS + ((jt + 1) << 6),           B + 8192);
            asm volatile("s_waitcnt vmcnt(2)" ::: "memory");
        } else {
            asm volatile("s_waitcnt vmcnt(0)" ::: "memory");
        }
        __builtin_amdgcn_s_barrier();
        __builtin_amdgcn_sched_barrier(0);

        char* buf = lds + 16384 * p;

        // ---- St = K·Q^T (rows j, cols q); 1-term ----
        f32x4 S[4];
        __builtin_amdgcn_s_setprio(1);
#pragma unroll
        for (int m = 0; m < 4; ++m) {
            f32x4 acc = {0.f, 0.f, 0.f, 0.f};
#pragma unroll
            for (int ks = 0; ks < 2; ++ks) {
                const int row = lq + 16 * m;
                const int ch  = ((lg + 4 * ks) ^ (row & 7)) << 4;
                bf16x8 kh = *(const bf16x8*)(buf + row * 128 + ch);
                acc = MFMA16(kh, qh[ks], acc);
            }
            S[m] = acc;
        }
        __builtin_amdgcn_s_setprio(0);

        // ---- softmax numerator (exp2, fixed max) ----
        float ps[4][4];
#pragma unroll
        for (int m = 0; m < 4; ++m)
#pragma unroll
            for (int r = 0; r < 4; ++r) {
                const float p2 = __builtin_exp2f(S[m][r]);
                ps[m][r] = p2;
                l_lane += p2;
            }

        // ---- P -> per-wave LDS region (bf16) ----
#pragma unroll
        for (int f = 0; f < 4; ++f) {
            union { bf16 hh[4]; uint2 u; } pu;
            pu.hh[0] = (bf16)ps[f][0];
            pu.hh[1] = (bf16)ps[f][1];
            pu.hh[2] = (bf16)ps[f][2];
            pu.hh[3] = (bf16)ps[f][3];
            *(uint2*)(Pw + lq * 128 + (((2 * f + (lg >> 1)) ^ (lq & 7)) << 4) + ((lg & 1) << 3)) = pu.u;
        }

        // ---- Ot += Vt · Pt ----
#pragma unroll
        for (int ks = 0; ks < 2; ++ks) {
            bf16x8 pb = *(const bf16x8*)(Pw + lq * 128 + (((lg + 4 * ks) ^ (lq & 7)) << 4));
            __builtin_amdgcn_s_setprio(1);
#pragma unroll
            for (int m = 0; m < 4; ++m) {
                const int row = lq + 16 * m;
                bf16x8 va = *(const bf16x8*)(buf + 8192 + row * 128 + (((lg + 4 * ks) ^ (row & 7)) << 4));
                Oa[m] = MFMA16(va, pb, Oa[m]);
            }
            __builtin_amdgcn_s_setprio(0);
        }

        asm volatile("s_waitcnt lgkmcnt(0)" ::: "memory");
        __builtin_amdgcn_s_barrier();
        __builtin_amdgcn_sched_barrier(0);
    }

    // epilogue: cross-lane l-reduction (lanes lq, lq+16, lq+32, lq+48)
    float l_run = l_lane;
    l_run += __shfl_xor(l_run, 16);
    l_run += __shfl_xor(l_run, 32);
    const float inv = 1.0f / l_run;
    const int i = i0 + w * 16 + lq;
    const size_t obase = ((size_t)(b * NN) + i) * HID + h * DDIM;
#pragma unroll
    for (int m = 0; m < 4; ++m) {
        bf16x4 ov;
#pragma unroll
        for (int r = 0; r < 4; ++r) ov[r] = (bf16)(Oa[m][r] * inv);
        *(bf16x4*)(Ot + obase + 16 * m + 4 * lg) = ov;
    }
}

// ---------------------------------------------------------------------------
extern "C" void kernel_launch(void* const* d_in, const int* in_sizes, int n_in,
                              void* d_out, int out_size, void* d_ws, size_t ws_size,
                              hipStream_t stream)
{
    const float* x_q   = (const float*)d_in[0];
    const float* x_kv  = (const float*)d_in[1];
    const float* w_q   = (const float*)d_in[2];
    const float* w_kv  = (const float*)d_in[3];
    const float* w_out = (const float*)d_in[4];
    float* out = (float*)d_out;

    char* ws = (char*)d_ws;
    bf16* Xtq   = (bf16*)(ws + 0);
    bf16* Ot    = (bf16*)(ws + 0);
    bf16* Xtkv  = (bf16*)(ws + 5242880);
    bf16* Wqh   = (bf16*)(ws + 15728640);
    bf16* Wkvh  = (bf16*)(ws + 16384000);
    bf16* Wouth = (bf16*)(ws + 19005440);
    bf16* Woutl = (bf16*)(ws + 19398656);
    bf16* Qhi   = (bf16*)(ws + 19791872);
    bf16* Khi   = (bf16*)(ws + 36569088);
    bf16* Vt    = (bf16*)(ws + 53346304);

    dim3 blk(256);
    prep_kernel<<<dim3(2912), blk, 0, stream>>>(x_q, x_kv, w_q, w_kv, w_out,
                                                Xtq, Xtkv, Wqh, Wkvh,
                                                Wouth, Woutl);
    gemm_qkv_kernel<<<dim3(768), blk, 0, stream>>>(Xtq, Xtkv, Wqh, Wkvh,
                                                   Qhi, Khi, Vt);
    attn_kernel<<<dim3(512), dim3(512), 0, stream>>>(Qhi, Khi, Vt, Ot);
    outproj_kernel<<<dim3(3, 8, 8), blk, 0, stream>>>(Ot, Wouth, Woutl, out);
}